// Round 2
// baseline (14918.965 us; speedup 1.0000x reference)
//
#include <hip/hip_runtime.h>
#include <hip/hip_bf16.h>
#include <math.h>

// ============================================================================
// GPT forward, B=2 T=2048 D=768 H=12 HD=64 L=4 V=32000.
// Round 1 fix: ALL float tensors are fp32 (per reference dtypes / harness
// template). Round 0's bf16-bit reinterpretation of fp32 buffers created NaN
// bf16 patterns from mantissa bits -> NaN logits. fp32 in / fp32 out now.
// ============================================================================

#define D_   768
#define T_   2048
#define NB_  4096   // B*T rows
#define HD_  64
#define NH_  12
#define NL_  4
#define V_   32000
#define EPS_ 1e-5f

// ---------------------------------------------------------------------------
// Embedding: x[row,:] = tok_emb[ids[row],:] + pos_emb[row % T,:]
// ---------------------------------------------------------------------------
__global__ __launch_bounds__(256) void embed_kernel(
    const int* __restrict__ ids, const float* __restrict__ tok,
    const float* __restrict__ pos, float* __restrict__ x) {
    int row = blockIdx.x;
    int t = row & (T_ - 1);
    int id = ids[row];
    const float* tr = tok + (size_t)id * D_;
    const float* pr = pos + (size_t)t * D_;
    float* xr = x + (size_t)row * D_;
    for (int i = threadIdx.x; i < D_; i += 256)
        xr[i] = tr[i] + pr[i];
}

// ---------------------------------------------------------------------------
// LayerNorm: one 256-thread block per row, D=768 -> 3 elems/thread
// ---------------------------------------------------------------------------
__global__ __launch_bounds__(256) void ln_kernel(
    const float* __restrict__ x, const float* __restrict__ g,
    const float* __restrict__ b, float* __restrict__ o) {
    int row = blockIdx.x, tid = threadIdx.x;
    const float* xr = x + (size_t)row * D_;
    float v0 = xr[tid], v1 = xr[tid + 256], v2 = xr[tid + 512];
    __shared__ float red[256];
    red[tid] = v0 + v1 + v2;
    __syncthreads();
    for (int off = 128; off > 0; off >>= 1) {
        if (tid < off) red[tid] += red[tid + off];
        __syncthreads();
    }
    float mu = red[0] * (1.0f / D_);
    __syncthreads();
    float d0 = v0 - mu, d1 = v1 - mu, d2 = v2 - mu;
    red[tid] = d0 * d0 + d1 * d1 + d2 * d2;
    __syncthreads();
    for (int off = 128; off > 0; off >>= 1) {
        if (tid < off) red[tid] += red[tid + off];
        __syncthreads();
    }
    float inv = rsqrtf(red[0] * (1.0f / D_) + EPS_);
    float* orow = o + (size_t)row * D_;
    orow[tid]       = d0 * inv * g[tid]       + b[tid];
    orow[tid + 256] = d1 * inv * g[tid + 256] + b[tid + 256];
    orow[tid + 512] = d2 * inv * g[tid + 512] + b[tid + 512];
}

// ---------------------------------------------------------------------------
// GEMM: C[M,N] = A[M,K] @ W[N,K]^T (+bias)(+gelu)(+residual)
// All fp32. 64x64 tile, BK=16, 256 threads, 4x4 per thread.
// ---------------------------------------------------------------------------
template <bool GELU>
__global__ __launch_bounds__(256) void gemm_kernel(
    const float* __restrict__ A, const float* __restrict__ W,
    const float* __restrict__ bias, const float* __restrict__ resid,
    float* __restrict__ C, int M, int N, int K) {
    // pad 68: row stride 272B (16B-multiple) so float4 LDS reads stay aligned
    __shared__ float As[16][68];
    __shared__ float Ws[16][68];
    int bn = blockIdx.x * 64, bm = blockIdx.y * 64;
    int tid = threadIdx.x;
    int tx = tid & 15, ty = tid >> 4;
    int lm = tid >> 2, lk = (tid & 3) << 2;
    float acc[4][4] = {{0.f}};
    const float* aPtr = A + (size_t)(bm + lm) * K + lk;
    const float* wPtr = W + (size_t)(bn + lm) * K + lk;
    for (int k0 = 0; k0 < K; k0 += 16) {
        float4 av = *(const float4*)(aPtr + k0);
        float4 wv = *(const float4*)(wPtr + k0);
        As[lk + 0][lm] = av.x; As[lk + 1][lm] = av.y;
        As[lk + 2][lm] = av.z; As[lk + 3][lm] = av.w;
        Ws[lk + 0][lm] = wv.x; Ws[lk + 1][lm] = wv.y;
        Ws[lk + 2][lm] = wv.z; Ws[lk + 3][lm] = wv.w;
        __syncthreads();
#pragma unroll
        for (int kk = 0; kk < 16; ++kk) {
            float4 ra = *(const float4*)&As[kk][ty * 4];
            float4 rb = *(const float4*)&Ws[kk][tx * 4];
            acc[0][0] += ra.x * rb.x; acc[0][1] += ra.x * rb.y;
            acc[0][2] += ra.x * rb.z; acc[0][3] += ra.x * rb.w;
            acc[1][0] += ra.y * rb.x; acc[1][1] += ra.y * rb.y;
            acc[1][2] += ra.y * rb.z; acc[1][3] += ra.y * rb.w;
            acc[2][0] += ra.z * rb.x; acc[2][1] += ra.z * rb.y;
            acc[2][2] += ra.z * rb.z; acc[2][3] += ra.z * rb.w;
            acc[3][0] += ra.w * rb.x; acc[3][1] += ra.w * rb.y;
            acc[3][2] += ra.w * rb.z; acc[3][3] += ra.w * rb.w;
        }
        __syncthreads();
    }
#pragma unroll
    for (int i = 0; i < 4; ++i) {
        int m = bm + ty * 4 + i;
#pragma unroll
        for (int j = 0; j < 4; ++j) {
            int n = bn + tx * 4 + j;
            float v = acc[i][j];
            if (bias) v += bias[n];
            if (GELU) v = 0.5f * v * (1.0f + erff(v * 0.70710678118654752f));
            if (resid) v += resid[(size_t)m * N + n];
            C[(size_t)m * N + n] = v;
        }
    }
}

// ---------------------------------------------------------------------------
// Causal attention: one 64-lane wave per (q-row t, head h, batch b).
// qkv rows: [q(768) | k(768) | v(768)], head slice h*64..h*64+63.
// ---------------------------------------------------------------------------
__global__ __launch_bounds__(64) void attn_kernel(
    const float* __restrict__ qkv, float* __restrict__ attout) {
    int t = blockIdx.x, h = blockIdx.y, b = blockIdx.z;
    int lane = threadIdx.x;
    __shared__ float q_s[64];
    __shared__ float p_s[T_];
    const float* base = qkv + (size_t)b * T_ * 2304;
    q_s[lane] = base[(size_t)t * 2304 + h * 64 + lane];
    __syncthreads();
    const float scale = 0.125f;  // 1/sqrt(64)
    float lmax = -INFINITY;
    for (int k = lane; k <= t; k += 64) {
        const float* kr = base + (size_t)k * 2304 + 768 + h * 64;
        float dot = 0.f;
#pragma unroll
        for (int d = 0; d < 64; d += 4) {
            float4 kv = *(const float4*)(kr + d);
            dot += q_s[d] * kv.x + q_s[d + 1] * kv.y + q_s[d + 2] * kv.z +
                   q_s[d + 3] * kv.w;
        }
        dot *= scale;
        p_s[k] = dot;
        lmax = fmaxf(lmax, dot);
    }
#pragma unroll
    for (int off = 32; off > 0; off >>= 1)
        lmax = fmaxf(lmax, __shfl_xor(lmax, off, 64));
    float lsum = 0.f;
    for (int k = lane; k <= t; k += 64) {
        float p = __expf(p_s[k] - lmax);
        p_s[k] = p;
        lsum += p;
    }
#pragma unroll
    for (int off = 32; off > 0; off >>= 1) lsum += __shfl_xor(lsum, off, 64);
    __syncthreads();  // all p_s visible to all lanes
    float inv = 1.0f / lsum;
    float acc = 0.f;
    const float* vbase = base + 1536 + h * 64 + lane;
    for (int k = 0; k <= t; ++k) acc += p_s[k] * vbase[(size_t)k * 2304];
    attout[((size_t)(b * T_ + t)) * D_ + h * 64 + lane] = acc * inv;
}

// ---------------------------------------------------------------------------
extern "C" void kernel_launch(void* const* d_in, const int* in_sizes, int n_in,
                              void* d_out, int out_size, void* d_ws,
                              size_t ws_size, hipStream_t stream) {
    const int*   ids  = (const int*)d_in[0];
    const float* tok  = (const float*)d_in[1];
    const float* pos  = (const float*)d_in[2];
    const float* ln1g = (const float*)d_in[3];
    const float* ln1b = (const float*)d_in[4];
    const float* Wqkv = (const float*)d_in[5];
    const float* bqkv = (const float*)d_in[6];
    const float* Wprj = (const float*)d_in[7];
    const float* bprj = (const float*)d_in[8];
    const float* ln2g = (const float*)d_in[9];
    const float* ln2b = (const float*)d_in[10];
    const float* W1   = (const float*)d_in[11];
    const float* b1   = (const float*)d_in[12];
    const float* W2   = (const float*)d_in[13];
    const float* b2   = (const float*)d_in[14];
    const float* lnfg = (const float*)d_in[15];
    const float* lnfb = (const float*)d_in[16];

    float* x   = (float*)d_ws;                  // 4096x768
    float* h   = x + (size_t)NB_ * D_;          // 4096x768
    float* qkv = h + (size_t)NB_ * D_;          // 4096x2304
    float* att = qkv + (size_t)NB_ * 3 * D_;    // 4096x768
    float* ff  = att + (size_t)NB_ * D_;        // 4096x3072

    embed_kernel<<<NB_, 256, 0, stream>>>(ids, tok, pos, x);

    for (int l = 0; l < NL_; ++l) {
        ln_kernel<<<NB_, 256, 0, stream>>>(x, ln1g + l * D_, ln1b + l * D_, h);
        gemm_kernel<false><<<dim3(2304 / 64, NB_ / 64), 256, 0, stream>>>(
            h, Wqkv + (size_t)l * 2304 * D_, bqkv + l * 2304, nullptr, qkv,
            NB_, 2304, D_);
        attn_kernel<<<dim3(T_, NH_, 2), 64, 0, stream>>>(qkv, att);
        gemm_kernel<false><<<dim3(D_ / 64, NB_ / 64), 256, 0, stream>>>(
            att, Wprj + (size_t)l * D_ * D_, bprj + l * D_, x, x, NB_, D_, D_);
        ln_kernel<<<NB_, 256, 0, stream>>>(x, ln2g + l * D_, ln2b + l * D_, h);
        gemm_kernel<true><<<dim3(3072 / 64, NB_ / 64), 256, 0, stream>>>(
            h, W1 + (size_t)l * 3072 * D_, b1 + l * 3072, nullptr, ff,
            NB_, 3072, D_);
        gemm_kernel<false><<<dim3(D_ / 64, NB_ / 64), 256, 0, stream>>>(
            ff, W2 + (size_t)l * D_ * 3072, b2 + l * D_, x, x, NB_, D_, 3072);
    }

    ln_kernel<<<NB_, 256, 0, stream>>>(x, lnfg, lnfb, h);
    gemm_kernel<false><<<dim3(V_ / 64, NB_ / 64), 256, 0, stream>>>(
        h, tok, nullptr, nullptr, (float*)d_out, NB_, V_, D_);
}